// Round 1
// baseline (330.036 us; speedup 1.0000x reference)
//
#include <hip/hip_runtime.h>
#include <float.h>
#include <math.h>

// Problem constants
#define B  4
#define L  2048
#define D  512      // d_model == input dim
#define K4 4        // top-k = int(log(64)) = 4
#define LCHUNKS 8

// ws layout (bytes). Total ~33.2 MB.
#define VMIX_OFF   0u                       // B*L*D f32 = 16 MB
#define T_OFF      (16u*1024u*1024u)        // B*L*D f32 = 16 MB
#define SMALL_OFF  (32u*1024u*1024u)
#define QPART_OFF  (SMALL_OFF)              // B*LCHUNKS*D f32 = 64 KB
#define MW_OFF     (SMALL_OFF + 65536u)     // D*D f32 = 1 MB
#define U_OFF      (MW_OFF + 1048576u)      // B*D f32 = 8 KB
#define SC_OFF     (U_OFF + 8192u)          // B*L f32 = 32 KB
#define W_OFF      (SC_OFF + 32768u)        // B*K4 f32
#define I_OFF      (W_OFF + 64u)            // B*K4 i32

// ---------------- 1) partial column sums of queries ----------------
// qpart[b][lc][d] = sum over 256 rows of queries[b, lc*256 + l, d]
__global__ void k_qpart(const float* __restrict__ q, float* __restrict__ qpart) {
    int b = blockIdx.x, dc = blockIdx.y, lc = blockIdx.z;
    int d = dc * 256 + threadIdx.x;
    const float* p = q + ((size_t)b * L + (size_t)lc * (L / LCHUNKS)) * D + d;
    float acc = 0.f;
#pragma unroll 4
    for (int l = 0; l < L / LCHUNKS; ++l) acc += p[(size_t)l * D];
    qpart[((b * LCHUNKS) + lc) * D + d] = acc;
}

// ---------------- 2) Mw = wk @ wq^T : Mw[i][j] = sum_m wk[i][m]*wq[j][m] ----------------
__global__ void k_mw(const float* __restrict__ wk, const float* __restrict__ wq,
                     float* __restrict__ Mw) {
    __shared__ float As[64][33];
    __shared__ float Bs[64][33];
    int i0 = blockIdx.x * 64, j0 = blockIdx.y * 64;
    int tid = threadIdx.x, tx = tid & 15, ty = tid >> 4;
    float acc[4][4] = {};
    for (int k0 = 0; k0 < D; k0 += 32) {
        for (int e = tid; e < 64 * 32; e += 256) {
            int row = e >> 5, col = e & 31;
            As[row][col] = wk[(size_t)(i0 + row) * D + k0 + col];
            Bs[row][col] = wq[(size_t)(j0 + row) * D + k0 + col];
        }
        __syncthreads();
#pragma unroll
        for (int kk = 0; kk < 32; ++kk) {
            float a[4], bb[4];
#pragma unroll
            for (int i = 0; i < 4; ++i) a[i] = As[ty * 4 + i][kk];
#pragma unroll
            for (int j = 0; j < 4; ++j) bb[j] = Bs[tx * 4 + j][kk];
#pragma unroll
            for (int i = 0; i < 4; ++i)
#pragma unroll
                for (int j = 0; j < 4; ++j) acc[i][j] += a[i] * bb[j];
        }
        __syncthreads();
    }
    for (int i = 0; i < 4; ++i) {
        float4 v = make_float4(acc[i][0], acc[i][1], acc[i][2], acc[i][3]);
        *(float4*)&Mw[(size_t)(i0 + ty * 4 + i) * D + j0 + tx * 4] = v;
    }
}

// ---------------- 3) u[b][i] = (1/16384) * sum_d Mw[i][d] * qsum[b][d] ----------------
__global__ void k_u(const float* __restrict__ Mw, const float* __restrict__ qpart,
                    float* __restrict__ u) {
    __shared__ float qs[D];
    int b = blockIdx.x;
    int tid = threadIdx.x;
    for (int d = tid; d < D; d += 256) {
        float s = 0.f;
        for (int c = 0; c < LCHUNKS; ++c) s += qpart[((b * LCHUNKS) + c) * D + d];
        qs[d] = s;
    }
    __syncthreads();
    int wave = tid >> 6, lane = tid & 63;
    for (int rr = 0; rr < 4; ++rr) {
        int row = blockIdx.y * 16 + wave * 4 + rr;
        float acc = 0.f;
#pragma unroll
        for (int k = 0; k < 8; ++k) acc += Mw[(size_t)row * D + lane + 64 * k] * qs[lane + 64 * k];
        for (int m = 32; m; m >>= 1) acc += __shfl_xor(acc, m, 64);
        if (lane == 0) u[b * D + row] = acc * (1.f / 16384.f);
    }
}

// ---------------- 4) scores[b][j] = keys[b,j,:] . u[b,:] ----------------
__global__ void k_scores(const float* __restrict__ keys, const float* __restrict__ u,
                         float* __restrict__ sc) {
    __shared__ float us[D];
    int b = blockIdx.x;
    int tid = threadIdx.x;
    for (int d = tid; d < D; d += 256) us[d] = u[b * D + d];
    __syncthreads();
    int wave = tid >> 6, lane = tid & 63;
    int j = blockIdx.y * 4 + wave;
    const float* kp = keys + ((size_t)b * L + j) * D;
    float acc = 0.f;
#pragma unroll
    for (int k = 0; k < 8; ++k) acc += kp[lane + 64 * k] * us[lane + 64 * k];
    for (int m = 32; m; m >>= 1) acc += __shfl_xor(acc, m, 64);
    if (lane == 0) sc[b * L + j] = acc;
}

// ---------------- 5) top-4 + softmax per batch ----------------
__global__ void k_top4(const float* __restrict__ sc, float* __restrict__ wout,
                       int* __restrict__ iout) {
    __shared__ float sv[L];
    __shared__ float rv[256];
    __shared__ int ri[256];
    __shared__ float topv[K4];
    __shared__ int topi[K4];
    int b = blockIdx.x, tid = threadIdx.x;
    for (int i = tid; i < L; i += 256) sv[i] = sc[b * L + i];
    __syncthreads();
    for (int it = 0; it < K4; ++it) {
        float bv = -FLT_MAX;
        int bi = L;
        for (int i = 0; i < L / 256; ++i) {
            int idx = tid + i * 256;
            float v = sv[idx];
            if (v > bv) { bv = v; bi = idx; }   // ascending scan: strict > keeps smallest idx
        }
        rv[tid] = bv; ri[tid] = bi;
        __syncthreads();
        for (int off = 128; off > 0; off >>= 1) {
            if (tid < off) {
                float v2 = rv[tid + off]; int i2 = ri[tid + off];
                if (v2 > rv[tid] || (v2 == rv[tid] && i2 < ri[tid])) { rv[tid] = v2; ri[tid] = i2; }
            }
            __syncthreads();
        }
        if (tid == 0) { topv[it] = rv[0]; topi[it] = ri[0]; sv[ri[0]] = -FLT_MAX; }
        __syncthreads();
    }
    if (tid == 0) {
        float mx = topv[0];
        for (int i = 1; i < K4; ++i) mx = fmaxf(mx, topv[i]);
        float s = 0.f, e[K4];
        for (int i = 0; i < K4; ++i) { e[i] = expf(topv[i] - mx); s += e[i]; }
        for (int i = 0; i < K4; ++i) { wout[b * K4 + i] = e[i] / s; iout[b * K4 + i] = topi[i]; }
    }
}

// ---------------- 6) vmix[b,l,:] = sum_j w_j * values[b,(l+idx_j)%L,:] ----------------
__global__ void k_vmix(const float* __restrict__ values, const float* __restrict__ wb,
                       const int* __restrict__ ib, float* __restrict__ vmix) {
    __shared__ float wsh[K4];
    __shared__ int ish[K4];
    size_t t = (size_t)blockIdx.x * 256 + threadIdx.x;  // float4 index
    int b = (int)(t >> 18);                             // 128*2048 = 2^18 float4 per batch
    if (threadIdx.x < K4) { wsh[threadIdx.x] = wb[b * K4 + threadIdx.x]; ish[threadIdx.x] = ib[b * K4 + threadIdx.x]; }
    __syncthreads();
    int c4 = (int)(t & 127);
    int l = (int)((t >> 7) & (L - 1));
    const float4* vp = (const float4*)values;
    float4 r = make_float4(0.f, 0.f, 0.f, 0.f);
#pragma unroll
    for (int j = 0; j < K4; ++j) {
        int ls = (l + ish[j]) & (L - 1);
        float4 x = vp[((size_t)b * L + ls) * 128 + c4];
        r.x += wsh[j] * x.x; r.y += wsh[j] * x.y; r.z += wsh[j] * x.z; r.w += wsh[j] * x.w;
    }
    ((float4*)vmix)[t] = r;
}

// ---------------- 7) T = vmix @ wv  (M=8192, N=512, K=512) ----------------
__global__ void k_gemm_nn(const float* __restrict__ A, const float* __restrict__ Bm,
                          float* __restrict__ C) {
    __shared__ float As[64][33];   // [m][k]
    __shared__ float Bs[32][65];   // [k][n]
    int m0 = blockIdx.x * 64, n0 = blockIdx.y * 64;
    int tid = threadIdx.x, tx = tid & 15, ty = tid >> 4;
    float acc[4][4] = {};
    for (int k0 = 0; k0 < D; k0 += 32) {
        for (int e = tid; e < 64 * 32; e += 256) {
            int row = e >> 5, col = e & 31;
            As[row][col] = A[(size_t)(m0 + row) * D + k0 + col];
        }
        for (int e = tid; e < 32 * 64; e += 256) {
            int row = e >> 6, col = e & 63;
            Bs[row][col] = Bm[(size_t)(k0 + row) * D + n0 + col];
        }
        __syncthreads();
#pragma unroll
        for (int kk = 0; kk < 32; ++kk) {
            float a[4], bb[4];
#pragma unroll
            for (int i = 0; i < 4; ++i) a[i] = As[ty * 4 + i][kk];
#pragma unroll
            for (int j = 0; j < 4; ++j) bb[j] = Bs[kk][tx * 4 + j];
#pragma unroll
            for (int i = 0; i < 4; ++i)
#pragma unroll
                for (int j = 0; j < 4; ++j) acc[i][j] += a[i] * bb[j];
        }
        __syncthreads();
    }
    for (int i = 0; i < 4; ++i) {
        float4 v = make_float4(acc[i][0], acc[i][1], acc[i][2], acc[i][3]);
        *(float4*)&C[(size_t)(m0 + ty * 4 + i) * D + n0 + tx * 4] = v;
    }
}

// ---------------- 8) out[b, perm(m,s), n] = sum_c T[b, s*512+c, m] * wo[c, n] ----------------
__global__ void k_gemm_tn_perm(const float* __restrict__ Tm, const float* __restrict__ wo,
                               float* __restrict__ out) {
    __shared__ float As[32][65];  // [c][m]
    __shared__ float Bs[32][65];  // [c][n]
    int m0 = blockIdx.x * 64, n0 = blockIdx.y * 64;
    int bs = blockIdx.z;
    int b = bs >> 2, s = bs & 3;
    const float* Ab = Tm + ((size_t)b * L + (size_t)s * 512) * D;
    int tid = threadIdx.x, tx = tid & 15, ty = tid >> 4;
    float acc[4][4] = {};
    for (int k0 = 0; k0 < D; k0 += 32) {
        for (int e = tid; e < 32 * 64; e += 256) {
            int row = e >> 6, col = e & 63;
            As[row][col] = Ab[(size_t)(k0 + row) * D + m0 + col];
            Bs[row][col] = wo[(size_t)(k0 + row) * D + n0 + col];
        }
        __syncthreads();
#pragma unroll
        for (int kk = 0; kk < 32; ++kk) {
            float a[4], bb[4];
#pragma unroll
            for (int i = 0; i < 4; ++i) a[i] = As[kk][ty * 4 + i];
#pragma unroll
            for (int j = 0; j < 4; ++j) bb[j] = Bs[kk][tx * 4 + j];
#pragma unroll
            for (int i = 0; i < 4; ++i)
#pragma unroll
                for (int j = 0; j < 4; ++j) acc[i][j] += a[i] * bb[j];
        }
        __syncthreads();
    }
    for (int i = 0; i < 4; ++i) {
        int m = m0 + ty * 4 + i;
        int r = ((m & 63) << 5) | ((m >> 6) << 2) | s;  // row permutation from transpose+reshape
        float4 v = make_float4(acc[i][0], acc[i][1], acc[i][2], acc[i][3]);
        *(float4*)&out[((size_t)b * L + r) * D + n0 + tx * 4] = v;
    }
}

extern "C" void kernel_launch(void* const* d_in, const int* in_sizes, int n_in,
                              void* d_out, int out_size, void* d_ws, size_t ws_size,
                              hipStream_t stream) {
    const float* queries = (const float*)d_in[0];
    const float* keys    = (const float*)d_in[1];
    const float* values  = (const float*)d_in[2];
    const float* wq      = (const float*)d_in[3];
    const float* wk      = (const float*)d_in[4];
    const float* wv      = (const float*)d_in[5];
    const float* wo      = (const float*)d_in[6];
    float* out = (float*)d_out;
    char* ws = (char*)d_ws;

    float* vmix  = (float*)(ws + VMIX_OFF);
    float* Tbuf  = (float*)(ws + T_OFF);
    float* qpart = (float*)(ws + QPART_OFF);
    float* Mw    = (float*)(ws + MW_OFF);
    float* u     = (float*)(ws + U_OFF);
    float* sc    = (float*)(ws + SC_OFF);
    float* wbuf  = (float*)(ws + W_OFF);
    int*   ibuf  = (int*)(ws + I_OFF);

    k_qpart<<<dim3(B, 2, LCHUNKS), 256, 0, stream>>>(queries, qpart);
    k_mw<<<dim3(8, 8), 256, 0, stream>>>(wk, wq, Mw);
    k_u<<<dim3(B, 32), 256, 0, stream>>>(Mw, qpart, u);
    k_scores<<<dim3(B, 512), 256, 0, stream>>>(keys, u, sc);
    k_top4<<<B, 256, 0, stream>>>(sc, wbuf, ibuf);
    k_vmix<<<4096, 256, 0, stream>>>(values, wbuf, ibuf, vmix);
    k_gemm_nn<<<dim3(128, 8), 256, 0, stream>>>(vmix, wv, Tbuf);
    k_gemm_tn_perm<<<dim3(8, 8, 16), 256, 0, stream>>>(Tbuf, wo, out);
}

// Round 2
// 75.934 us; speedup vs baseline: 4.3464x; 4.3464x over previous
//
#include <hip/hip_runtime.h>
#include <hip/hip_bf16.h>
#include <float.h>
#include <math.h>

#define B  4
#define L  2048
#define D  512
#define K4 4
#define QCH 32   // l-chunks for qpart

typedef __attribute__((ext_vector_type(8))) short  bf16x8;
typedef __attribute__((ext_vector_type(4))) float  f32x4;

// ---- ws layout (bytes) ----
#define VMIXB_OFF  0u                  // B*L*D bf16 = 8 MB
#define TT_OFF     8388608u            // B*512*2048 bf16 = 8 MB
#define WVT_OFF    16777216u           // 512*512 bf16
#define WOT_OFF    17301504u
#define QPART_OFF  17825792u           // B*QCH*512 f32
#define TPART_OFF  18087936u           // B*8*512 f32
#define U_OFF      18153472u           // B*512 f32
#define SC_OFF     18161664u           // B*L f32
#define W_OFF      18194432u
#define I_OFF      18194496u

static __device__ __forceinline__ unsigned short f2b(float f) {
    __hip_bfloat16 h = __float2bfloat16(f);
    return *reinterpret_cast<unsigned short*>(&h);
}

// ---------------- 1) qpart[b][lc][d] = sum over 64 rows of queries ----------------
__global__ void k_qpart(const float* __restrict__ q, float* __restrict__ qpart) {
    int b = blockIdx.x, dc = blockIdx.y, lc = blockIdx.z;
    int d = dc * 256 + threadIdx.x;
    const float* p = q + ((size_t)b * L + (size_t)lc * (L / QCH)) * D + d;
    float acc = 0.f;
#pragma unroll 4
    for (int l = 0; l < L / QCH; ++l) acc += p[(size_t)l * D];
    qpart[((b * QCH) + lc) * D + d] = acc;
}

// ---------------- 2) weight transposes -> bf16 [n][k] ----------------
__global__ void k_wt(const float* __restrict__ wv, const float* __restrict__ wo,
                     unsigned short* __restrict__ wvT, unsigned short* __restrict__ woT) {
    __shared__ float s[32][33];
    const float* src = (blockIdx.z == 0) ? wv : wo;
    unsigned short* dst = (blockIdx.z == 0) ? wvT : woT;
    int c0 = blockIdx.x * 32, n0 = blockIdx.y * 32;
    int tid = threadIdx.x, col = tid & 31, r8 = tid >> 5;
#pragma unroll
    for (int rr = 0; rr < 4; ++rr) {
        int r = rr * 8 + r8;
        s[r][col] = src[(size_t)(c0 + r) * D + n0 + col];
    }
    __syncthreads();
#pragma unroll
    for (int rr = 0; rr < 4; ++rr) {
        int r = rr * 8 + r8;
        dst[(size_t)(n0 + r) * D + c0 + col] = f2b(s[col][r]);
    }
}

// ---------------- 3) tpart[b][jc][m] = sum_{j in chunk} wq[j][m] * qsum[b][j] ----------------
__global__ void k_tpart(const float* __restrict__ wq, const float* __restrict__ qpart,
                        float* __restrict__ tpart) {
    __shared__ float part[256];
    __shared__ float qs[64];
    int b = blockIdx.x, jc = blockIdx.y, tid = threadIdx.x;
    int jj = tid & 63, cg = tid >> 6;
    float p = 0.f;
#pragma unroll
    for (int c = cg * 8; c < cg * 8 + 8; ++c)
        p += qpart[((b * QCH) + c) * D + jc * 64 + jj];
    part[tid] = p;
    __syncthreads();
    if (tid < 64) qs[tid] = part[tid] + part[tid + 64] + part[tid + 128] + part[tid + 192];
    __syncthreads();
    float a0 = 0.f, a1 = 0.f;
#pragma unroll 8
    for (int j = 0; j < 64; ++j) {
        const float* wr = wq + (size_t)(jc * 64 + j) * D;
        float qv = qs[j];
        a0 += wr[tid] * qv;
        a1 += wr[tid + 256] * qv;
    }
    tpart[((b * 8) + jc) * D + tid] = a0;
    tpart[((b * 8) + jc) * D + tid + 256] = a1;
}

// ---------------- 4) u[b][i] = (1/16384) sum_m wk[i][m] * t[b][m] ----------------
__global__ void k_uvec(const float* __restrict__ wk, const float* __restrict__ tpart,
                       float* __restrict__ u) {
    __shared__ float ts[D];
    int b = blockIdx.x, tid = threadIdx.x;
    for (int d = tid; d < D; d += 256) {
        float s = 0.f;
#pragma unroll
        for (int c = 0; c < 8; ++c) s += tpart[((b * 8) + c) * D + d];
        ts[d] = s;
    }
    __syncthreads();
    int wave = tid >> 6, lane = tid & 63;
#pragma unroll
    for (int rr = 0; rr < 4; ++rr) {
        int row = blockIdx.y * 16 + wave * 4 + rr;
        float acc = 0.f;
#pragma unroll
        for (int k = 0; k < 8; ++k) acc += wk[(size_t)row * D + lane + 64 * k] * ts[lane + 64 * k];
        for (int m = 32; m; m >>= 1) acc += __shfl_xor(acc, m, 64);
        if (lane == 0) u[b * D + row] = acc * (1.f / 16384.f);
    }
}

// ---------------- 5) scores[b][j] = keys[b,j,:] . u[b,:] ----------------
__global__ void k_scores(const float* __restrict__ keys, const float* __restrict__ u,
                         float* __restrict__ sc) {
    __shared__ float us[D];
    int b = blockIdx.x, tid = threadIdx.x;
    for (int d = tid; d < D; d += 256) us[d] = u[b * D + d];
    __syncthreads();
    int wave = tid >> 6, lane = tid & 63;
    int j = blockIdx.y * 4 + wave;
    const float* kp = keys + ((size_t)b * L + j) * D;
    float acc = 0.f;
#pragma unroll
    for (int k = 0; k < 8; ++k) acc += kp[lane + 64 * k] * us[lane + 64 * k];
    for (int m = 32; m; m >>= 1) acc += __shfl_xor(acc, m, 64);
    if (lane == 0) sc[b * L + j] = acc;
}

// ---------------- 6) top-4 + softmax ----------------
__global__ void k_top4(const float* __restrict__ sc, float* __restrict__ wout,
                       int* __restrict__ iout) {
    __shared__ float sv[L];
    __shared__ float rv[256];
    __shared__ int ri[256];
    __shared__ float topv[K4];
    __shared__ int topi[K4];
    int b = blockIdx.x, tid = threadIdx.x;
    for (int i = tid; i < L; i += 256) sv[i] = sc[b * L + i];
    __syncthreads();
    for (int it = 0; it < K4; ++it) {
        float bv = -FLT_MAX;
        int bi = L;
        for (int i = 0; i < L / 256; ++i) {
            int idx = tid + i * 256;
            float v = sv[idx];
            if (v > bv) { bv = v; bi = idx; }
        }
        rv[tid] = bv; ri[tid] = bi;
        __syncthreads();
        for (int off = 128; off > 0; off >>= 1) {
            if (tid < off) {
                float v2 = rv[tid + off]; int i2 = ri[tid + off];
                if (v2 > rv[tid] || (v2 == rv[tid] && i2 < ri[tid])) { rv[tid] = v2; ri[tid] = i2; }
            }
            __syncthreads();
        }
        if (tid == 0) { topv[it] = rv[0]; topi[it] = ri[0]; sv[ri[0]] = -FLT_MAX; }
        __syncthreads();
    }
    if (tid == 0) {
        float mx = topv[0];
        for (int i = 1; i < K4; ++i) mx = fmaxf(mx, topv[i]);
        float s = 0.f, e[K4];
        for (int i = 0; i < K4; ++i) { e[i] = expf(topv[i] - mx); s += e[i]; }
        for (int i = 0; i < K4; ++i) { wout[b * K4 + i] = e[i] / s; iout[b * K4 + i] = topi[i]; }
    }
}

// ---------------- 7) vmixb[b,l,:] = bf16( sum_j w_j * values[b,(l+idx_j)%L,:] ) ----------------
__global__ void k_vmixb(const float* __restrict__ values, const float* __restrict__ wb,
                        const int* __restrict__ ib, uint4* __restrict__ vmixb) {
    __shared__ float wsh[K4];
    __shared__ int ish[K4];
    size_t t = (size_t)blockIdx.x * 256 + threadIdx.x;  // one 8-elem bf16 group
    int b = (int)(t >> 17);                              // 2048*64 groups per batch
    if (threadIdx.x < K4) { wsh[threadIdx.x] = wb[b * K4 + threadIdx.x]; ish[threadIdx.x] = ib[b * K4 + threadIdx.x]; }
    __syncthreads();
    int l  = (int)((t >> 6) & (L - 1));
    int g8 = (int)(t & 63);
    const float4* vp = (const float4*)values;
    float4 r0 = make_float4(0.f, 0.f, 0.f, 0.f), r1 = r0;
#pragma unroll
    for (int j = 0; j < K4; ++j) {
        int ls = (l + ish[j]) & (L - 1);
        const float4* p = vp + ((size_t)b * L + ls) * 128 + g8 * 2;
        float4 x0 = p[0], x1 = p[1];
        float w = wsh[j];
        r0.x += w * x0.x; r0.y += w * x0.y; r0.z += w * x0.z; r0.w += w * x0.w;
        r1.x += w * x1.x; r1.y += w * x1.y; r1.z += w * x1.z; r1.w += w * x1.w;
    }
    uint4 o;
    o.x = (unsigned)f2b(r0.x) | ((unsigned)f2b(r0.y) << 16);
    o.y = (unsigned)f2b(r0.z) | ((unsigned)f2b(r0.w) << 16);
    o.z = (unsigned)f2b(r1.x) | ((unsigned)f2b(r1.y) << 16);
    o.w = (unsigned)f2b(r1.z) | ((unsigned)f2b(r1.w) << 16);
    vmixb[t] = o;
}

// ---------------- 8) GEMM1: Tt[b][n][l'] = bf16( sum_k vmixb[b*L+l'][k] * wvT[n][k] ) ----------------
__global__ __launch_bounds__(256) void k_gemm1(const unsigned short* __restrict__ A,
                                               const unsigned short* __restrict__ Bt,
                                               unsigned short* __restrict__ Tt) {
    __shared__ __align__(16) unsigned short As[128][40];
    __shared__ __align__(16) unsigned short Bs[128][40];
    int m0 = blockIdx.x * 128, n0 = blockIdx.y * 128;
    int tid = threadIdx.x;
    int wave = tid >> 6, lane = tid & 63;
    int wr = wave >> 1, wc = wave & 1;
    int lg = lane >> 4, lr = lane & 15;
    f32x4 acc[4][4];
#pragma unroll
    for (int i = 0; i < 4; ++i)
#pragma unroll
        for (int j = 0; j < 4; ++j) acc[i][j] = (f32x4){0.f, 0.f, 0.f, 0.f};

    int row = tid >> 2, kc = tid & 3;
    for (int k0 = 0; k0 < D; k0 += 32) {
        uint4 va0 = *(const uint4*)(A  + (size_t)(m0 + row)      * D + k0 + kc * 8);
        uint4 va1 = *(const uint4*)(A  + (size_t)(m0 + 64 + row) * D + k0 + kc * 8);
        uint4 vb0 = *(const uint4*)(Bt + (size_t)(n0 + row)      * D + k0 + kc * 8);
        uint4 vb1 = *(const uint4*)(Bt + (size_t)(n0 + 64 + row) * D + k0 + kc * 8);
        *(uint4*)&As[row][kc * 8] = va0;
        *(uint4*)&As[64 + row][kc * 8] = va1;
        *(uint4*)&Bs[row][kc * 8] = vb0;
        *(uint4*)&Bs[64 + row][kc * 8] = vb1;
        __syncthreads();
        bf16x8 a[4], b[4];
#pragma unroll
        for (int i = 0; i < 4; ++i) a[i] = *(const bf16x8*)&As[wr * 64 + i * 16 + lr][lg * 8];
#pragma unroll
        for (int j = 0; j < 4; ++j) b[j] = *(const bf16x8*)&Bs[wc * 64 + j * 16 + lr][lg * 8];
#pragma unroll
        for (int i = 0; i < 4; ++i)
#pragma unroll
            for (int j = 0; j < 4; ++j)
                acc[i][j] = __builtin_amdgcn_mfma_f32_16x16x32_bf16(a[i], b[j], acc[i][j], 0, 0, 0);
        __syncthreads();
    }
    int bb = m0 >> 11;
#pragma unroll
    for (int i = 0; i < 4; ++i) {
        int lp = ((m0 + wr * 64 + i * 16 + lg * 4) & (L - 1));
#pragma unroll
        for (int j = 0; j < 4; ++j) {
            int cn = n0 + wc * 64 + j * 16 + lr;
            uint2 pk;
            pk.x = (unsigned)f2b(acc[i][j][0]) | ((unsigned)f2b(acc[i][j][1]) << 16);
            pk.y = (unsigned)f2b(acc[i][j][2]) | ((unsigned)f2b(acc[i][j][3]) << 16);
            *(uint2*)&Tt[((size_t)bb * D + cn) * L + lp] = pk;
        }
    }
}

// ---------------- 9) GEMM2: out[b][perm(m,s)][n] = sum_c Tt[b][m][s*512+c] * woT[n][c] ----------------
__global__ __launch_bounds__(256) void k_gemm2(const unsigned short* __restrict__ Tt,
                                               const unsigned short* __restrict__ Bt,
                                               float* __restrict__ out) {
    __shared__ __align__(16) unsigned short As[128][40];
    __shared__ __align__(16) unsigned short Bs[128][40];
    int m0 = blockIdx.x * 128, n0 = blockIdx.y * 128;
    int bs = blockIdx.z;
    int bb = bs >> 2, s = bs & 3;
    const unsigned short* Ab = Tt + (size_t)bb * D * L + (size_t)s * 512;
    int tid = threadIdx.x;
    int wave = tid >> 6, lane = tid & 63;
    int wr = wave >> 1, wc = wave & 1;
    int lg = lane >> 4, lr = lane & 15;
    f32x4 acc[4][4];
#pragma unroll
    for (int i = 0; i < 4; ++i)
#pragma unroll
        for (int j = 0; j < 4; ++j) acc[i][j] = (f32x4){0.f, 0.f, 0.f, 0.f};

    int row = tid >> 2, kc = tid & 3;
    for (int k0 = 0; k0 < D; k0 += 32) {
        uint4 va0 = *(const uint4*)(Ab + (size_t)(m0 + row)      * L + k0 + kc * 8);
        uint4 va1 = *(const uint4*)(Ab + (size_t)(m0 + 64 + row) * L + k0 + kc * 8);
        uint4 vb0 = *(const uint4*)(Bt + (size_t)(n0 + row)      * D + k0 + kc * 8);
        uint4 vb1 = *(const uint4*)(Bt + (size_t)(n0 + 64 + row) * D + k0 + kc * 8);
        *(uint4*)&As[row][kc * 8] = va0;
        *(uint4*)&As[64 + row][kc * 8] = va1;
        *(uint4*)&Bs[row][kc * 8] = vb0;
        *(uint4*)&Bs[64 + row][kc * 8] = vb1;
        __syncthreads();
        bf16x8 a[4], b[4];
#pragma unroll
        for (int i = 0; i < 4; ++i) a[i] = *(const bf16x8*)&As[wr * 64 + i * 16 + lr][lg * 8];
#pragma unroll
        for (int j = 0; j < 4; ++j) b[j] = *(const bf16x8*)&Bs[wc * 64 + j * 16 + lr][lg * 8];
#pragma unroll
        for (int i = 0; i < 4; ++i)
#pragma unroll
            for (int j = 0; j < 4; ++j)
                acc[i][j] = __builtin_amdgcn_mfma_f32_16x16x32_bf16(a[i], b[j], acc[i][j], 0, 0, 0);
        __syncthreads();
    }
#pragma unroll
    for (int i = 0; i < 4; ++i) {
#pragma unroll
        for (int j = 0; j < 4; ++j) {
            int n = n0 + wc * 64 + j * 16 + lr;
#pragma unroll
            for (int r = 0; r < 4; ++r) {
                int m = m0 + wr * 64 + i * 16 + lg * 4 + r;
                int rr = ((m & 63) << 5) | ((m >> 6) << 2) | s;
                out[((size_t)bb * L + rr) * D + n] = acc[i][j][r];
            }
        }
    }
}

extern "C" void kernel_launch(void* const* d_in, const int* in_sizes, int n_in,
                              void* d_out, int out_size, void* d_ws, size_t ws_size,
                              hipStream_t stream) {
    const float* queries = (const float*)d_in[0];
    const float* keys    = (const float*)d_in[1];
    const float* values  = (const float*)d_in[2];
    const float* wq      = (const float*)d_in[3];
    const float* wk      = (const float*)d_in[4];
    const float* wv      = (const float*)d_in[5];
    const float* wo      = (const float*)d_in[6];
    float* out = (float*)d_out;
    char* ws = (char*)d_ws;

    unsigned short* vmixb = (unsigned short*)(ws + VMIXB_OFF);
    unsigned short* Tt    = (unsigned short*)(ws + TT_OFF);
    unsigned short* wvT   = (unsigned short*)(ws + WVT_OFF);
    unsigned short* woT   = (unsigned short*)(ws + WOT_OFF);
    float* qpart = (float*)(ws + QPART_OFF);
    float* tpart = (float*)(ws + TPART_OFF);
    float* u     = (float*)(ws + U_OFF);
    float* sc    = (float*)(ws + SC_OFF);
    float* wbuf  = (float*)(ws + W_OFF);
    int*   ibuf  = (int*)(ws + I_OFF);

    k_qpart<<<dim3(B, 2, QCH), 256, 0, stream>>>(queries, qpart);
    k_wt<<<dim3(16, 16, 2), 256, 0, stream>>>(wv, wo, wvT, woT);
    k_tpart<<<dim3(B, 8), 256, 0, stream>>>(wq, qpart, tpart);
    k_uvec<<<dim3(B, 32), 256, 0, stream>>>(wk, tpart, u);
    k_scores<<<dim3(B, 512), 256, 0, stream>>>(keys, u, sc);
    k_top4<<<B, 256, 0, stream>>>(sc, wbuf, ibuf);
    k_vmixb<<<2048, 256, 0, stream>>>(values, wbuf, ibuf, (uint4*)vmixb);
    k_gemm1<<<dim3(64, 4), 256, 0, stream>>>(vmixb, wvT, Tt);
    k_gemm2<<<dim3(4, 4, 16), 256, 0, stream>>>(Tt, woT, out);
}